// Round 5
// baseline (626.157 us; speedup 1.0000x reference)
//
#include <hip/hip_runtime.h>

typedef __bf16 bf16x8 __attribute__((ext_vector_type(8)));
typedef __bf16 bf16x4 __attribute__((ext_vector_type(4)));
typedef float  f32x4  __attribute__((ext_vector_type(4)));

#define MFMA16(a, b, c) __builtin_amdgcn_mfma_f32_16x16x32_bf16((a), (b), (c), 0, 0, 0)

__device__ __forceinline__ float sigm(float x) { return 1.0f / (1.0f + __expf(-x)); }

// ---- packed bf16 weight layout (element offsets inside d_ws) ----
enum : int {
  ENC_W0_OFF  = 0,        // 16 x 128 x 256
  ENC_W1_OFF  = 524288,   // 16 x 64 x 128
  ENC_W2_OFF  = 655360,   // 16 x 32 x 64
  DEC_W0_OFF  = 688128,   // 16 x 64 x 32
  DEC_W1_OFF  = 720896,   // 16 x 128 x 64
  DEC_W2_OFF  = 851968,   // 16 x 256 x 128
  COMP_W0_OFF = 1376256,  // 256 x 512  (folded [z,z])
  COMP_W1_OFF = 1507328,  // 128 x 768
  COMP_W2_OFF = 1605632,  // 64 x 640
  COMP_W3_OFF = 1646592,  // 32 x 576
  COMP_W4_OFF = 1665024,  // 16 x 544
  COMP_W5_OFF = 1673728,  // 32 x 544  (528 padded to 544, pad = 0)
  DCMP_W0_OFF = 1691136,  // 256 x 32  (folded)
  DCMP_W1_OFF = 1699328,  // 128 x 288
  DCMP_W2_OFF = 1736192,  // 64 x 160
  DCMP_W3_OFF = 1746432,  // 32 x 96
  DCMP_W4_OFF = 1749504,  // 16 x 64
  DCMP_W5_OFF = 1750528,  // 512 x 64  (48 padded to 64, pad = 0)
  W_TOTAL     = 1783296,
};

#define ZS_BYTES_OFF (4u * 1024u * 1024u)  // z_stack, overwritten in-place by z_stack_hat

// =============================== weight prep ===============================
__global__ void prep_kernel(
    const float* __restrict__ ew0, const float* __restrict__ ew1, const float* __restrict__ ew2,
    const float* __restrict__ dw0, const float* __restrict__ dw1, const float* __restrict__ dw2,
    const float* __restrict__ cw0, const float* __restrict__ cw1, const float* __restrict__ cw2,
    const float* __restrict__ cw3, const float* __restrict__ cw4, const float* __restrict__ cw5,
    const float* __restrict__ xw0, const float* __restrict__ xw1, const float* __restrict__ xw2,
    const float* __restrict__ xw3, const float* __restrict__ xw4, const float* __restrict__ xw5,
    __bf16* __restrict__ wb)
{
  for (int i = blockIdx.x * blockDim.x + threadIdx.x; i < W_TOTAL; i += gridDim.x * blockDim.x) {
    float v;
    if      (i < ENC_W1_OFF)  v = ew0[i - ENC_W0_OFF];
    else if (i < ENC_W2_OFF)  v = ew1[i - ENC_W1_OFF];
    else if (i < DEC_W0_OFF)  v = ew2[i - ENC_W2_OFF];
    else if (i < DEC_W1_OFF)  v = dw0[i - DEC_W0_OFF];
    else if (i < DEC_W2_OFF)  v = dw1[i - DEC_W1_OFF];
    else if (i < COMP_W0_OFF) v = dw2[i - DEC_W2_OFF];
    else if (i < COMP_W1_OFF) { int t = i - COMP_W0_OFF; int o = t >> 9, c = t & 511;
                                v = cw0[o * 1024 + c] + cw0[o * 1024 + 512 + c]; }
    else if (i < COMP_W2_OFF) v = cw1[i - COMP_W1_OFF];
    else if (i < COMP_W3_OFF) v = cw2[i - COMP_W2_OFF];
    else if (i < COMP_W4_OFF) v = cw3[i - COMP_W3_OFF];
    else if (i < COMP_W5_OFF) v = cw4[i - COMP_W4_OFF];
    else if (i < DCMP_W0_OFF) { int t = i - COMP_W5_OFF; int o = t / 544, c = t % 544;
                                v = (c < 528) ? cw5[o * 528 + c] : 0.0f; }
    else if (i < DCMP_W1_OFF) { int t = i - DCMP_W0_OFF; int o = t >> 5, c = t & 31;
                                v = xw0[o * 64 + c] + xw0[o * 64 + 32 + c]; }
    else if (i < DCMP_W2_OFF) v = xw1[i - DCMP_W1_OFF];
    else if (i < DCMP_W3_OFF) v = xw2[i - DCMP_W2_OFF];
    else if (i < DCMP_W4_OFF) v = xw3[i - DCMP_W3_OFF];
    else if (i < DCMP_W5_OFF) v = xw4[i - DCMP_W4_OFF];
    else                      { int t = i - DCMP_W5_OFF; int o = t >> 6, c = t & 63;
                                v = (c < 48) ? xw5[o * 48 + c] : 0.0f; }
    wb[i] = (__bf16)v;
  }
}

// =============================== encoder ===================================
// Block = (64-row m-tile, one encoder e). 256 threads = 4 waves.
// LDS 50 KB (h2 aliases dead xs region) -> 3 blocks/CU for phase diversity.
__global__ __launch_bounds__(256, 3)
void enc_kernel(const float* __restrict__ x, const __bf16* __restrict__ wb,
                const float* __restrict__ b0, const float* __restrict__ b1,
                const float* __restrict__ b2, __bf16* __restrict__ zout)
{
  __shared__ __align__(16) char smem[51200];
  __bf16* xs = (__bf16*)smem;            // [64][264]; dead after L0
  __bf16* h1 = (__bf16*)(smem + 33792);  // [64][136]
  __bf16* h2 = (__bf16*)smem;            // [64][72], aliases xs (safe: written after sync#2)
  const int e = blockIdx.y;
  const int m0 = blockIdx.x * 64;
  const int tid = threadIdx.x;
  const int lane = tid & 63, wv = tid >> 6;
  const int l15 = lane & 15, hi8 = (lane >> 4) * 8, rloc = (lane >> 4) * 4;

  const float* xblk = x + (size_t)m0 * 4096 + e * 256;
  #pragma unroll
  for (int i = 0; i < 16; ++i) {
    int idx = tid + i * 256;
    int r = idx >> 6, c4 = (idx & 63) * 4;
    float4 v = *(const float4*)(xblk + (size_t)r * 4096 + c4);
    bf16x4 o = { (__bf16)v.x, (__bf16)v.y, (__bf16)v.z, (__bf16)v.w };
    *(bf16x4*)&xs[r * 264 + c4] = o;
  }
  __syncthreads();

  // L0: N=128, K=256. wave covers cols [wv*32, wv*32+32)
  {
    const __bf16* W = wb + ENC_W0_OFF + e * 32768;
    f32x4 acc[4][2];
    #pragma unroll
    for (int cf = 0; cf < 2; ++cf) {
      float bv = b0[e * 128 + wv * 32 + cf * 16 + l15];
      f32x4 b4 = {bv, bv, bv, bv};
      #pragma unroll
      for (int rf = 0; rf < 4; ++rf) acc[rf][cf] = b4;
    }
    #pragma unroll
    for (int ks = 0; ks < 8; ++ks) {
      bf16x8 a[4], bb[2];
      #pragma unroll
      for (int rf = 0; rf < 4; ++rf)
        a[rf] = *(const bf16x8*)&xs[(rf * 16 + l15) * 264 + ks * 32 + hi8];
      #pragma unroll
      for (int cf = 0; cf < 2; ++cf)
        bb[cf] = *(const bf16x8*)(W + (size_t)(wv * 32 + cf * 16 + l15) * 256 + ks * 32 + hi8);
      #pragma unroll
      for (int rf = 0; rf < 4; ++rf)
        #pragma unroll
        for (int cf = 0; cf < 2; ++cf)
          acc[rf][cf] = MFMA16(a[rf], bb[cf], acc[rf][cf]);
    }
    #pragma unroll
    for (int rf = 0; rf < 4; ++rf)
      #pragma unroll
      for (int cf = 0; cf < 2; ++cf)
        #pragma unroll
        for (int r = 0; r < 4; ++r)
          h1[(rf * 16 + rloc + r) * 136 + wv * 32 + cf * 16 + l15] = (__bf16)sigm(acc[rf][cf][r]);
  }
  __syncthreads();

  // L1: N=64, K=128. wave covers cols [wv*16, wv*16+16). h2 overwrites xs region.
  {
    const __bf16* W = wb + ENC_W1_OFF + e * 8192;
    f32x4 acc[4];
    float bv = b1[e * 64 + wv * 16 + l15];
    f32x4 b4 = {bv, bv, bv, bv};
    #pragma unroll
    for (int rf = 0; rf < 4; ++rf) acc[rf] = b4;
    #pragma unroll
    for (int ks = 0; ks < 4; ++ks) {
      bf16x8 bb = *(const bf16x8*)(W + (size_t)(wv * 16 + l15) * 128 + ks * 32 + hi8);
      #pragma unroll
      for (int rf = 0; rf < 4; ++rf) {
        bf16x8 a = *(const bf16x8*)&h1[(rf * 16 + l15) * 136 + ks * 32 + hi8];
        acc[rf] = MFMA16(a, bb, acc[rf]);
      }
    }
    #pragma unroll
    for (int rf = 0; rf < 4; ++rf)
      #pragma unroll
      for (int r = 0; r < 4; ++r)
        h2[(rf * 16 + rloc + r) * 72 + wv * 16 + l15] = (__bf16)sigm(acc[rf][r]);
  }
  __syncthreads();

  // L2: N=32, K=64, no sigmoid. waves 0,1.
  if (wv < 2) {
    const __bf16* W = wb + ENC_W2_OFF + e * 2048;
    f32x4 acc[4];
    float bv = b2[e * 32 + wv * 16 + l15];
    f32x4 b4 = {bv, bv, bv, bv};
    #pragma unroll
    for (int rf = 0; rf < 4; ++rf) acc[rf] = b4;
    #pragma unroll
    for (int ks = 0; ks < 2; ++ks) {
      bf16x8 bb = *(const bf16x8*)(W + (size_t)(wv * 16 + l15) * 64 + ks * 32 + hi8);
      #pragma unroll
      for (int rf = 0; rf < 4; ++rf) {
        bf16x8 a = *(const bf16x8*)&h2[(rf * 16 + l15) * 72 + ks * 32 + hi8];
        acc[rf] = MFMA16(a, bb, acc[rf]);
      }
    }
    #pragma unroll
    for (int rf = 0; rf < 4; ++rf)
      #pragma unroll
      for (int r = 0; r < 4; ++r)
        zout[(size_t)(m0 + rf * 16 + rloc + r) * 512 + e * 32 + wv * 16 + l15] = (__bf16)acc[rf][r];
  }
}

// ========================= middle (comp + decomp) ==========================
struct MidBias {
  const float *c0, *c1, *c2, *c3, *c4, *c5;
  const float *x0, *x1, *x2, *x3, *x4, *x5;
};

// One residual layer, 16 waves, all compile-time geometry. NT = N/16 col tiles.
// NT>=16: wave=col(s), all 64 rows. NT==8: (col, row-half). NT==4: (col,
// row-quarter). NT==2: 8 waves (col, row-quarter). NT==1: waves 0-3.
template<int NT, int KT, int ZKS, int ZLD, int SKS, int SLD, int DLD, bool SIG>
__device__ __forceinline__ void rlayer16(const __bf16* __restrict__ W, const float* __restrict__ bias,
                                         const __bf16* __restrict__ zp, const __bf16* __restrict__ sp,
                                         __bf16* __restrict__ dst,
                                         int wv, int l15, int hi8, int rloc)
{
  constexpr int NJ = (NT >= 16) ? NT / 16 : 1;
  constexpr int NR = (NT >= 16) ? 4 : ((NT == 8) ? 2 : 1);
  int c0, row0;
  if constexpr (NT >= 16)      { c0 = wv;     row0 = 0; }
  else if constexpr (NT == 8)  { c0 = wv & 7; row0 = (wv >> 3) * 32; }
  else if constexpr (NT == 4)  { c0 = wv & 3; row0 = (wv >> 2) * 16; }
  else if constexpr (NT == 2)  { if (wv >= 8) return; c0 = wv & 1; row0 = (wv >> 1) * 16; }
  else                         { if (wv >= 4) return; c0 = 0; row0 = wv * 16; }
  f32x4 acc[NR][NJ];
  #pragma unroll
  for (int j = 0; j < NJ; ++j) {
    float bv = bias[(c0 + 16 * j) * 16 + l15];
    f32x4 b4 = {bv, bv, bv, bv};
    #pragma unroll
    for (int rf = 0; rf < NR; ++rf) acc[rf][j] = b4;
  }
  #pragma unroll
  for (int ks = 0; ks < ZKS; ++ks) {
    bf16x8 a[NR];
    #pragma unroll
    for (int rf = 0; rf < NR; ++rf)
      a[rf] = *(const bf16x8*)&zp[(size_t)(row0 + rf * 16 + l15) * ZLD + ks * 32 + hi8];
    #pragma unroll
    for (int j = 0; j < NJ; ++j) {
      bf16x8 b = *(const bf16x8*)&W[(size_t)((c0 + 16 * j) * 16 + l15) * KT + ks * 32 + hi8];
      #pragma unroll
      for (int rf = 0; rf < NR; ++rf) acc[rf][j] = MFMA16(a[rf], b, acc[rf][j]);
    }
  }
  if constexpr (SKS > 0) {
    #pragma unroll
    for (int ks = 0; ks < SKS; ++ks) {
      bf16x8 a[NR];
      #pragma unroll
      for (int rf = 0; rf < NR; ++rf)
        a[rf] = *(const bf16x8*)&sp[(size_t)(row0 + rf * 16 + l15) * SLD + ks * 32 + hi8];
      #pragma unroll
      for (int j = 0; j < NJ; ++j) {
        bf16x8 b = *(const bf16x8*)&W[(size_t)((c0 + 16 * j) * 16 + l15) * KT + ZKS * 32 + ks * 32 + hi8];
        #pragma unroll
        for (int rf = 0; rf < NR; ++rf) acc[rf][j] = MFMA16(a[rf], b, acc[rf][j]);
      }
    }
  }
  #pragma unroll
  for (int j = 0; j < NJ; ++j)
    #pragma unroll
    for (int rf = 0; rf < NR; ++rf)
      #pragma unroll
      for (int r = 0; r < 4; ++r) {
        float v = acc[rf][j][r];
        dst[(size_t)(row0 + rf * 16 + rloc + r) * DLD + (c0 + 16 * j) * 16 + l15] =
            (__bf16)(SIG ? sigm(v) : v);
      }
}

// 64 rows, 1024 threads = 16 waves (4/SIMD TLP for L2-latency-bound b-loads).
// ~120 KB LDS -> 1 block/CU; grid 512 = 2 rounds/CU. In-place z_stack -> z_hat.
__global__ __launch_bounds__(1024, 4)
void mid_kernel(const __bf16* __restrict__ zin, const __bf16* __restrict__ wb,
                MidBias mb, __bf16* __restrict__ zhout)
{
  __shared__ __bf16 zs[64 * 520];
  __shared__ __bf16 sA[64 * 264];
  __shared__ __bf16 sB[64 * 136];
  __shared__ __bf16 zsm[64 * 40];
  const int tid = threadIdx.x;
  const int wv = tid >> 6, lane = tid & 63;
  const int l15 = lane & 15, hi8 = (lane >> 4) * 8, rloc = (lane >> 4) * 4;
  const int m0 = blockIdx.x * 64;

  #pragma unroll
  for (int i = 0; i < 4; ++i) {
    int idx = tid + i * 1024;
    int r = idx >> 6, c8 = (idx & 63) * 8;
    *(bf16x8*)&zs[r * 520 + c8] = *(const bf16x8*)(zin + (size_t)(m0 + r) * 512 + c8);
  }
  __syncthreads();
  // ---- compressor ----
  rlayer16<16, 512, 16, 520, 0,   0, 264, true >(wb + COMP_W0_OFF, mb.c0, zs, nullptr, sA, wv, l15, hi8, rloc); __syncthreads();
  rlayer16< 8, 768, 16, 520, 8, 264, 136, true >(wb + COMP_W1_OFF, mb.c1, zs, sA, sB, wv, l15, hi8, rloc); __syncthreads();
  rlayer16< 4, 640, 16, 520, 4, 136, 264, true >(wb + COMP_W2_OFF, mb.c2, zs, sB, sA, wv, l15, hi8, rloc); __syncthreads();
  rlayer16< 2, 576, 16, 520, 2, 264, 136, true >(wb + COMP_W3_OFF, mb.c3, zs, sA, sB, wv, l15, hi8, rloc); __syncthreads();
  rlayer16< 1, 544, 16, 520, 1, 136, 264, true >(wb + COMP_W4_OFF, mb.c4, zs, sB, sA, wv, l15, hi8, rloc);
  if (tid < 1024) { int i = tid; if (i < 64 * 16) sA[(i >> 4) * 264 + 16 + (i & 15)] = (__bf16)0.0f; }
  __syncthreads();
  rlayer16< 2, 544, 16, 520, 1, 264,  40, false>(wb + COMP_W5_OFF, mb.c5, zs, sA, zsm, wv, l15, hi8, rloc); __syncthreads();
  // ---- decompressor ----
  rlayer16<16,  32, 1, 40, 0,   0, 264, true >(wb + DCMP_W0_OFF, mb.x0, zsm, nullptr, sA, wv, l15, hi8, rloc); __syncthreads();
  rlayer16< 8, 288, 1, 40, 8, 264, 136, true >(wb + DCMP_W1_OFF, mb.x1, zsm, sA, sB, wv, l15, hi8, rloc); __syncthreads();
  rlayer16< 4, 160, 1, 40, 4, 136, 264, true >(wb + DCMP_W2_OFF, mb.x2, zsm, sB, sA, wv, l15, hi8, rloc); __syncthreads();
  rlayer16< 2,  96, 1, 40, 2, 264, 136, true >(wb + DCMP_W3_OFF, mb.x3, zsm, sA, sB, wv, l15, hi8, rloc); __syncthreads();
  rlayer16< 1,  64, 1, 40, 1, 136, 264, true >(wb + DCMP_W4_OFF, mb.x4, zsm, sB, sA, wv, l15, hi8, rloc);
  { int i = tid; if (i < 64 * 16) sA[(i >> 4) * 264 + 16 + (i & 15)] = (__bf16)0.0f; }
  __syncthreads();
  // final 512-wide layer writes z_stack_hat straight to global (in-place)
  rlayer16<32,  64, 1, 40, 1, 264, 512, false>(wb + DCMP_W5_OFF, mb.x5, zsm, sA,
                                               zhout + (size_t)m0 * 512, wv, l15, hi8, rloc);
}

// =============================== decoder ===================================
// Block = (64-row m-tile, one encoder e). 256 threads. 31.7 KB LDS -> 4/CU.
__global__ __launch_bounds__(256, 4)
void dec_kernel(const __bf16* __restrict__ zh, const __bf16* __restrict__ wb,
                const float* __restrict__ b0, const float* __restrict__ b1,
                const float* __restrict__ b2, float* __restrict__ out)
{
  __shared__ __bf16 zsl[64 * 40];
  __shared__ __bf16 h1[64 * 72];
  __shared__ __bf16 h2[64 * 136];
  const int e = blockIdx.y;
  const int m0 = blockIdx.x * 64;
  const int tid = threadIdx.x;
  const int lane = tid & 63, wv = tid >> 6;
  const int l15 = lane & 15, hi8 = (lane >> 4) * 8, rloc = (lane >> 4) * 4;

  {
    int r = tid >> 2, c8 = (tid & 3) * 8;
    *(bf16x8*)&zsl[r * 40 + c8] = *(const bf16x8*)(zh + (size_t)(m0 + r) * 512 + e * 32 + c8);
  }
  __syncthreads();

  // L0: N=64, K=32. wave -> cols [wv*16, +16), all 64 rows
  {
    const __bf16* W = wb + DEC_W0_OFF + e * 2048;
    f32x4 acc[4];
    float bv = b0[e * 64 + wv * 16 + l15];
    f32x4 b4 = {bv, bv, bv, bv};
    #pragma unroll
    for (int rf = 0; rf < 4; ++rf) acc[rf] = b4;
    bf16x8 bb = *(const bf16x8*)(W + (size_t)(wv * 16 + l15) * 32 + hi8);
    #pragma unroll
    for (int rf = 0; rf < 4; ++rf) {
      bf16x8 a = *(const bf16x8*)&zsl[(rf * 16 + l15) * 40 + hi8];
      acc[rf] = MFMA16(a, bb, acc[rf]);
    }
    #pragma unroll
    for (int rf = 0; rf < 4; ++rf)
      #pragma unroll
      for (int r = 0; r < 4; ++r)
        h1[(rf * 16 + rloc + r) * 72 + wv * 16 + l15] = (__bf16)sigm(acc[rf][r]);
  }
  __syncthreads();

  // L1: N=128, K=64. wave -> cols [wv*32, +32)
  {
    const __bf16* W = wb + DEC_W1_OFF + e * 8192;
    f32x4 acc[4][2];
    #pragma unroll
    for (int cf = 0; cf < 2; ++cf) {
      float bv = b1[e * 128 + wv * 32 + cf * 16 + l15];
      f32x4 b4 = {bv, bv, bv, bv};
      #pragma unroll
      for (int rf = 0; rf < 4; ++rf) acc[rf][cf] = b4;
    }
    #pragma unroll
    for (int ks = 0; ks < 2; ++ks) {
      bf16x8 b0v = *(const bf16x8*)(W + (size_t)(wv * 32 + l15) * 64 + ks * 32 + hi8);
      bf16x8 b1v = *(const bf16x8*)(W + (size_t)(wv * 32 + 16 + l15) * 64 + ks * 32 + hi8);
      #pragma unroll
      for (int rf = 0; rf < 4; ++rf) {
        bf16x8 a = *(const bf16x8*)&h1[(rf * 16 + l15) * 72 + ks * 32 + hi8];
        acc[rf][0] = MFMA16(a, b0v, acc[rf][0]);
        acc[rf][1] = MFMA16(a, b1v, acc[rf][1]);
      }
    }
    #pragma unroll
    for (int rf = 0; rf < 4; ++rf)
      #pragma unroll
      for (int cf = 0; cf < 2; ++cf)
        #pragma unroll
        for (int r = 0; r < 4; ++r)
          h2[(rf * 16 + rloc + r) * 136 + wv * 32 + cf * 16 + l15] = (__bf16)sigm(acc[rf][cf][r]);
  }
  __syncthreads();

  // L2: N=256, K=128, fp32 out. wave -> cols [wv*64, +64) in two 32-col passes
  {
    const __bf16* W = wb + DEC_W2_OFF + e * 32768;
    #pragma unroll 1
    for (int pass = 0; pass < 2; ++pass) {
      const int cb = wv * 64 + pass * 32;
      f32x4 acc[4][2];
      #pragma unroll
      for (int cf = 0; cf < 2; ++cf) {
        float bv = b2[e * 256 + cb + cf * 16 + l15];
        f32x4 b4 = {bv, bv, bv, bv};
        #pragma unroll
        for (int rf = 0; rf < 4; ++rf) acc[rf][cf] = b4;
      }
      #pragma unroll
      for (int ks = 0; ks < 4; ++ks) {
        bf16x8 b0v = *(const bf16x8*)(W + (size_t)(cb + l15) * 128 + ks * 32 + hi8);
        bf16x8 b1v = *(const bf16x8*)(W + (size_t)(cb + 16 + l15) * 128 + ks * 32 + hi8);
        #pragma unroll
        for (int rf = 0; rf < 4; ++rf) {
          bf16x8 a = *(const bf16x8*)&h2[(rf * 16 + l15) * 136 + ks * 32 + hi8];
          acc[rf][0] = MFMA16(a, b0v, acc[rf][0]);
          acc[rf][1] = MFMA16(a, b1v, acc[rf][1]);
        }
      }
      #pragma unroll
      for (int cf = 0; cf < 2; ++cf)
        #pragma unroll
        for (int rf = 0; rf < 4; ++rf)
          #pragma unroll
          for (int r = 0; r < 4; ++r)
            out[(size_t)(m0 + rf * 16 + rloc + r) * 4096 + e * 256 + cb + cf * 16 + l15] =
                acc[rf][cf][r];
    }
  }
}

// =============================== launcher ==================================
extern "C" void kernel_launch(void* const* d_in, const int* in_sizes, int n_in,
                              void* d_out, int out_size, void* d_ws, size_t ws_size,
                              hipStream_t stream) {
  (void)in_sizes; (void)n_in; (void)out_size; (void)ws_size;
  const float* x   = (const float*)d_in[0];
  const float* ew0 = (const float*)d_in[1];  const float* eb0 = (const float*)d_in[2];
  const float* ew1 = (const float*)d_in[3];  const float* eb1 = (const float*)d_in[4];
  const float* ew2 = (const float*)d_in[5];  const float* eb2 = (const float*)d_in[6];
  const float* dw0 = (const float*)d_in[7];  const float* db0 = (const float*)d_in[8];
  const float* dw1 = (const float*)d_in[9];  const float* db1 = (const float*)d_in[10];
  const float* dw2 = (const float*)d_in[11]; const float* db2 = (const float*)d_in[12];
  const float* cw[6]; const float* cb[6];
  for (int i = 0; i < 6; ++i) { cw[i] = (const float*)d_in[13 + 2 * i]; cb[i] = (const float*)d_in[14 + 2 * i]; }
  const float* xw[6]; const float* xb[6];
  for (int i = 0; i < 6; ++i) { xw[i] = (const float*)d_in[25 + 2 * i]; xb[i] = (const float*)d_in[26 + 2 * i]; }

  __bf16* wbuf   = (__bf16*)d_ws;
  __bf16* zstack = (__bf16*)((char*)d_ws + ZS_BYTES_OFF);  // z_stack, then z_stack_hat in-place
  float* out = (float*)d_out;

  prep_kernel<<<1024, 256, 0, stream>>>(ew0, ew1, ew2, dw0, dw1, dw2,
                                        cw[0], cw[1], cw[2], cw[3], cw[4], cw[5],
                                        xw[0], xw[1], xw[2], xw[3], xw[4], xw[5], wbuf);
  enc_kernel<<<dim3(512, 16), 256, 0, stream>>>(x, wbuf, eb0, eb1, eb2, zstack);
  MidBias mb = {cb[0], cb[1], cb[2], cb[3], cb[4], cb[5],
                xb[0], xb[1], xb[2], xb[3], xb[4], xb[5]};
  mid_kernel<<<512, 1024, 0, stream>>>(zstack, wbuf, mb, zstack);
  dec_kernel<<<dim3(512, 16), 256, 0, stream>>>(zstack, wbuf, db0, db1, db2, out);
}

// Round 6
// 487.625 us; speedup vs baseline: 1.2841x; 1.2841x over previous
//
#include <hip/hip_runtime.h>

typedef __bf16 bf16x8 __attribute__((ext_vector_type(8)));
typedef __bf16 bf16x4 __attribute__((ext_vector_type(4)));
typedef float  f32x4  __attribute__((ext_vector_type(4)));

#define MFMA16(a, b, c) __builtin_amdgcn_mfma_f32_16x16x32_bf16((a), (b), (c), 0, 0, 0)

__device__ __forceinline__ float sigm(float x) { return 1.0f / (1.0f + __expf(-x)); }

// ---- packed bf16 weight layout (element offsets inside d_ws) ----
enum : int {
  ENC_W0_OFF  = 0,        // 16 x 128 x 256
  ENC_W1_OFF  = 524288,   // 16 x 64 x 128
  ENC_W2_OFF  = 655360,   // 16 x 32 x 64
  DEC_W0_OFF  = 688128,   // 16 x 64 x 32
  DEC_W1_OFF  = 720896,   // 16 x 128 x 64
  DEC_W2_OFF  = 851968,   // 16 x 256 x 128
  COMP_W0_OFF = 1376256,  // 256 x 512  (folded [z,z])
  COMP_W1_OFF = 1507328,  // 128 x 768
  COMP_W2_OFF = 1605632,  // 64 x 640
  COMP_W3_OFF = 1646592,  // 32 x 576
  COMP_W4_OFF = 1665024,  // 16 x 544
  COMP_W5_OFF = 1673728,  // 32 x 544  (528 padded to 544, pad = 0)
  DCMP_W0_OFF = 1691136,  // 256 x 32  (folded)
  DCMP_W1_OFF = 1699328,  // 128 x 288
  DCMP_W2_OFF = 1736192,  // 64 x 160
  DCMP_W3_OFF = 1746432,  // 32 x 96
  DCMP_W4_OFF = 1749504,  // 16 x 64
  DCMP_W5_OFF = 1750528,  // 512 x 64  (48 padded to 64, pad = 0)
  W_TOTAL     = 1783296,
};

#define ZS_BYTES_OFF (4u * 1024u * 1024u)            // z_stack / z_stack_hat: 32 MB
#define Z_BYTES_OFF  (ZS_BYTES_OFF + 33554432u)      // z: 2 MB

// =============================== weight prep ===============================
__global__ void prep_kernel(
    const float* __restrict__ ew0, const float* __restrict__ ew1, const float* __restrict__ ew2,
    const float* __restrict__ dw0, const float* __restrict__ dw1, const float* __restrict__ dw2,
    const float* __restrict__ cw0, const float* __restrict__ cw1, const float* __restrict__ cw2,
    const float* __restrict__ cw3, const float* __restrict__ cw4, const float* __restrict__ cw5,
    const float* __restrict__ xw0, const float* __restrict__ xw1, const float* __restrict__ xw2,
    const float* __restrict__ xw3, const float* __restrict__ xw4, const float* __restrict__ xw5,
    __bf16* __restrict__ wb)
{
  for (int i = blockIdx.x * blockDim.x + threadIdx.x; i < W_TOTAL; i += gridDim.x * blockDim.x) {
    float v;
    if      (i < ENC_W1_OFF)  v = ew0[i - ENC_W0_OFF];
    else if (i < ENC_W2_OFF)  v = ew1[i - ENC_W1_OFF];
    else if (i < DEC_W0_OFF)  v = ew2[i - ENC_W2_OFF];
    else if (i < DEC_W1_OFF)  v = dw0[i - DEC_W0_OFF];
    else if (i < DEC_W2_OFF)  v = dw1[i - DEC_W1_OFF];
    else if (i < COMP_W0_OFF) v = dw2[i - DEC_W2_OFF];
    else if (i < COMP_W1_OFF) { int t = i - COMP_W0_OFF; int o = t >> 9, c = t & 511;
                                v = cw0[o * 1024 + c] + cw0[o * 1024 + 512 + c]; }
    else if (i < COMP_W2_OFF) v = cw1[i - COMP_W1_OFF];
    else if (i < COMP_W3_OFF) v = cw2[i - COMP_W2_OFF];
    else if (i < COMP_W4_OFF) v = cw3[i - COMP_W3_OFF];
    else if (i < COMP_W5_OFF) v = cw4[i - COMP_W4_OFF];
    else if (i < DCMP_W0_OFF) { int t = i - COMP_W5_OFF; int o = t / 544, c = t % 544;
                                v = (c < 528) ? cw5[o * 528 + c] : 0.0f; }
    else if (i < DCMP_W1_OFF) { int t = i - DCMP_W0_OFF; int o = t >> 5, c = t & 31;
                                v = xw0[o * 64 + c] + xw0[o * 64 + 32 + c]; }
    else if (i < DCMP_W2_OFF) v = xw1[i - DCMP_W1_OFF];
    else if (i < DCMP_W3_OFF) v = xw2[i - DCMP_W2_OFF];
    else if (i < DCMP_W4_OFF) v = xw3[i - DCMP_W3_OFF];
    else if (i < DCMP_W5_OFF) v = xw4[i - DCMP_W4_OFF];
    else                      { int t = i - DCMP_W5_OFF; int o = t >> 6, c = t & 63;
                                v = (c < 48) ? xw5[o * 48 + c] : 0.0f; }
    wb[i] = (__bf16)v;
  }
}

// =============================== encoder (R1 verbatim) =====================
__global__ __launch_bounds__(256, 2)
void enc_kernel(const float* __restrict__ x, const __bf16* __restrict__ wb,
                const float* __restrict__ b0, const float* __restrict__ b1,
                const float* __restrict__ b2, __bf16* __restrict__ zout)
{
  __shared__ __bf16 xs[64][264];
  __shared__ __bf16 h1[64][136];
  __shared__ __bf16 h2[64][72];
  const int e = blockIdx.y;
  const int m0 = blockIdx.x * 64;
  const int tid = threadIdx.x;
  const int lane = tid & 63, wv = tid >> 6;
  const int l15 = lane & 15, hi8 = (lane >> 4) * 8, rloc = (lane >> 4) * 4;

  const float* xblk = x + (size_t)m0 * 4096 + e * 256;
  #pragma unroll
  for (int i = 0; i < 16; ++i) {
    int idx = tid + i * 256;
    int r = idx >> 6, c4 = (idx & 63) * 4;
    float4 v = *(const float4*)(xblk + (size_t)r * 4096 + c4);
    bf16x4 o = { (__bf16)v.x, (__bf16)v.y, (__bf16)v.z, (__bf16)v.w };
    *(bf16x4*)&xs[r][c4] = o;
  }
  __syncthreads();

  // L0: N=128, K=256. wave covers cols [wv*32, wv*32+32)
  {
    const __bf16* W = wb + ENC_W0_OFF + e * 32768;
    f32x4 acc[4][2];
    #pragma unroll
    for (int cf = 0; cf < 2; ++cf) {
      float bv = b0[e * 128 + wv * 32 + cf * 16 + l15];
      f32x4 bvv = {bv, bv, bv, bv};
      #pragma unroll
      for (int rf = 0; rf < 4; ++rf) acc[rf][cf] = bvv;
    }
    #pragma unroll
    for (int ks = 0; ks < 8; ++ks) {
      bf16x8 a[4], bb[2];
      #pragma unroll
      for (int rf = 0; rf < 4; ++rf) a[rf] = *(const bf16x8*)&xs[rf * 16 + l15][ks * 32 + hi8];
      #pragma unroll
      for (int cf = 0; cf < 2; ++cf)
        bb[cf] = *(const bf16x8*)(W + (size_t)(wv * 32 + cf * 16 + l15) * 256 + ks * 32 + hi8);
      #pragma unroll
      for (int rf = 0; rf < 4; ++rf)
        #pragma unroll
        for (int cf = 0; cf < 2; ++cf)
          acc[rf][cf] = MFMA16(a[rf], bb[cf], acc[rf][cf]);
    }
    #pragma unroll
    for (int rf = 0; rf < 4; ++rf)
      #pragma unroll
      for (int cf = 0; cf < 2; ++cf)
        #pragma unroll
        for (int r = 0; r < 4; ++r)
          h1[rf * 16 + rloc + r][wv * 32 + cf * 16 + l15] = (__bf16)sigm(acc[rf][cf][r]);
  }
  __syncthreads();

  // L1: N=64, K=128
  {
    const __bf16* W = wb + ENC_W1_OFF + e * 8192;
    f32x4 acc[4];
    float bv = b1[e * 64 + wv * 16 + l15];
    f32x4 bvv = {bv, bv, bv, bv};
    #pragma unroll
    for (int rf = 0; rf < 4; ++rf) acc[rf] = bvv;
    #pragma unroll
    for (int ks = 0; ks < 4; ++ks) {
      bf16x8 a[4];
      #pragma unroll
      for (int rf = 0; rf < 4; ++rf) a[rf] = *(const bf16x8*)&h1[rf * 16 + l15][ks * 32 + hi8];
      bf16x8 bb = *(const bf16x8*)(W + (size_t)(wv * 16 + l15) * 128 + ks * 32 + hi8);
      #pragma unroll
      for (int rf = 0; rf < 4; ++rf) acc[rf] = MFMA16(a[rf], bb, acc[rf]);
    }
    #pragma unroll
    for (int rf = 0; rf < 4; ++rf)
      #pragma unroll
      for (int r = 0; r < 4; ++r)
        h2[rf * 16 + rloc + r][wv * 16 + l15] = (__bf16)sigm(acc[rf][r]);
  }
  __syncthreads();

  // L2: N=32, K=64, no sigmoid. waves 0,1 only.
  if (wv < 2) {
    const __bf16* W = wb + ENC_W2_OFF + e * 2048;
    f32x4 acc[4];
    float bv = b2[e * 32 + wv * 16 + l15];
    f32x4 bvv = {bv, bv, bv, bv};
    #pragma unroll
    for (int rf = 0; rf < 4; ++rf) acc[rf] = bvv;
    #pragma unroll
    for (int ks = 0; ks < 2; ++ks) {
      bf16x8 a[4];
      #pragma unroll
      for (int rf = 0; rf < 4; ++rf) a[rf] = *(const bf16x8*)&h2[rf * 16 + l15][ks * 32 + hi8];
      bf16x8 bb = *(const bf16x8*)(W + (size_t)(wv * 16 + l15) * 64 + ks * 32 + hi8);
      #pragma unroll
      for (int rf = 0; rf < 4; ++rf) acc[rf] = MFMA16(a[rf], bb, acc[rf]);
    }
    #pragma unroll
    for (int rf = 0; rf < 4; ++rf)
      #pragma unroll
      for (int r = 0; r < 4; ++r)
        zout[(size_t)(m0 + rf * 16 + rloc + r) * 512 + e * 32 + wv * 16 + l15] = (__bf16)acc[rf][r];
  }
}

// ==================== 8-wave residual layer (R4-verified) ==================
// NF = N/16 col tiles. NF>=16: wave=col(s), all 64 rows. NF==8: wave=col, all
// rows. NF==4: (col, row-half). NF==2: (col, row-quarter). NF==1: waves 0-3.
template<int NF, int KT, int ZKS, int ZLD, int SKS, int SLD, int DLD, bool SIG>
__device__ __forceinline__ void rlayer(const __bf16* __restrict__ W, const float* __restrict__ bias,
                                       const __bf16* __restrict__ zp, const __bf16* __restrict__ sp,
                                       __bf16* __restrict__ dst,
                                       int wv, int l15, int hi8, int rloc)
{
  constexpr int NJ = (NF >= 32) ? 4 : ((NF >= 16) ? 2 : 1);
  constexpr int NR = (NF >= 8) ? 4 : ((NF == 4) ? 2 : 1);
  int c0, row0;
  if constexpr (NF >= 8)       { c0 = wv;      row0 = 0; }
  else if constexpr (NF == 4)  { c0 = wv & 3;  row0 = (wv >> 2) * 32; }
  else if constexpr (NF == 2)  { c0 = wv & 1;  row0 = (wv >> 1) * 16; }
  else                         { if (wv >= 4) return; c0 = 0; row0 = wv * 16; }
  f32x4 acc[NR][NJ];
  #pragma unroll
  for (int j = 0; j < NJ; ++j) {
    float bv = bias[(c0 + 8 * j) * 16 + l15];
    f32x4 b4 = {bv, bv, bv, bv};
    #pragma unroll
    for (int rf = 0; rf < NR; ++rf) acc[rf][j] = b4;
  }
  #pragma unroll
  for (int ks = 0; ks < ZKS; ++ks) {
    bf16x8 a[NR];
    #pragma unroll
    for (int rf = 0; rf < NR; ++rf)
      a[rf] = *(const bf16x8*)&zp[(size_t)(row0 + rf * 16 + l15) * ZLD + ks * 32 + hi8];
    #pragma unroll
    for (int j = 0; j < NJ; ++j) {
      bf16x8 b = *(const bf16x8*)&W[(size_t)((c0 + 8 * j) * 16 + l15) * KT + ks * 32 + hi8];
      #pragma unroll
      for (int rf = 0; rf < NR; ++rf) acc[rf][j] = MFMA16(a[rf], b, acc[rf][j]);
    }
  }
  if constexpr (SKS > 0) {
    #pragma unroll
    for (int ks = 0; ks < SKS; ++ks) {
      bf16x8 a[NR];
      #pragma unroll
      for (int rf = 0; rf < NR; ++rf)
        a[rf] = *(const bf16x8*)&sp[(size_t)(row0 + rf * 16 + l15) * SLD + ks * 32 + hi8];
      #pragma unroll
      for (int j = 0; j < NJ; ++j) {
        bf16x8 b = *(const bf16x8*)&W[(size_t)((c0 + 8 * j) * 16 + l15) * KT + ZKS * 32 + ks * 32 + hi8];
        #pragma unroll
        for (int rf = 0; rf < NR; ++rf) acc[rf][j] = MFMA16(a[rf], b, acc[rf][j]);
      }
    }
  }
  #pragma unroll
  for (int j = 0; j < NJ; ++j)
    #pragma unroll
    for (int rf = 0; rf < NR; ++rf)
      #pragma unroll
      for (int r = 0; r < 4; ++r) {
        float v = acc[rf][j][r];
        dst[(size_t)(row0 + rf * 16 + rloc + r) * DLD + (c0 + 8 * j) * 16 + l15] =
            (__bf16)(SIG ? sigm(v) : v);
      }
}

// =============================== compressor ================================
// 64 rows, 512 threads = 8 waves (2/SIMD, 2x R1's TLP). ~120 KB LDS, 1/CU.
__global__ __launch_bounds__(512, 2)
void comp_kernel(const __bf16* __restrict__ zin, const __bf16* __restrict__ wb,
                 const float* __restrict__ cb0, const float* __restrict__ cb1,
                 const float* __restrict__ cb2, const float* __restrict__ cb3,
                 const float* __restrict__ cb4, const float* __restrict__ cb5,
                 __bf16* __restrict__ zout)
{
  __shared__ __bf16 zs[64 * 520];
  __shared__ __bf16 sA[64 * 264];
  __shared__ __bf16 sB[64 * 136];
  const int tid = threadIdx.x;
  const int wv = tid >> 6, lane = tid & 63;
  const int l15 = lane & 15, hi8 = (lane >> 4) * 8, rloc = (lane >> 4) * 4;
  const int m0 = blockIdx.x * 64;

  #pragma unroll
  for (int i = 0; i < 8; ++i) {
    int idx = tid + i * 512;
    int r = idx >> 6, c8 = (idx & 63) * 8;
    *(bf16x8*)&zs[r * 520 + c8] = *(const bf16x8*)(zin + (size_t)(m0 + r) * 512 + c8);
  }
  __syncthreads();
  rlayer<16, 512, 16, 520, 0,   0, 264, true >(wb + COMP_W0_OFF, cb0, zs, nullptr, sA, wv, l15, hi8, rloc); __syncthreads();
  rlayer< 8, 768, 16, 520, 8, 264, 136, true >(wb + COMP_W1_OFF, cb1, zs, sA, sB, wv, l15, hi8, rloc); __syncthreads();
  rlayer< 4, 640, 16, 520, 4, 136, 264, true >(wb + COMP_W2_OFF, cb2, zs, sB, sA, wv, l15, hi8, rloc); __syncthreads();
  rlayer< 2, 576, 16, 520, 2, 264, 136, true >(wb + COMP_W3_OFF, cb3, zs, sA, sB, wv, l15, hi8, rloc); __syncthreads();
  rlayer< 1, 544, 16, 520, 1, 136, 264, true >(wb + COMP_W4_OFF, cb4, zs, sB, sA, wv, l15, hi8, rloc);
  for (int i = tid; i < 64 * 16; i += 512) sA[(i >> 4) * 264 + 16 + (i & 15)] = (__bf16)0.0f;
  __syncthreads();
  // final: z (64x32) straight to global
  rlayer< 2, 544, 16, 520, 1, 264, 32, false>(wb + COMP_W5_OFF, cb5, zs, sA,
                                              zout + (size_t)m0 * 32, wv, l15, hi8, rloc);
}

// =============================== decompressor ==============================
// 64 rows, 512 threads = 8 waves. ~55 KB LDS -> 2 blocks/CU (4 waves/SIMD).
__global__ __launch_bounds__(512, 4)
void decomp_kernel(const __bf16* __restrict__ zin, const __bf16* __restrict__ wb,
                   const float* __restrict__ xb0, const float* __restrict__ xb1,
                   const float* __restrict__ xb2, const float* __restrict__ xb3,
                   const float* __restrict__ xb4, const float* __restrict__ xb5,
                   __bf16* __restrict__ zhout)
{
  __shared__ __bf16 zsm[64 * 40];
  __shared__ __bf16 sA[64 * 264];
  __shared__ __bf16 sB[64 * 136];
  const int tid = threadIdx.x;
  const int wv = tid >> 6, lane = tid & 63;
  const int l15 = lane & 15, hi8 = (lane >> 4) * 8, rloc = (lane >> 4) * 4;
  const int m0 = blockIdx.x * 64;

  if (tid < 256) {
    int r = tid >> 2, c8 = (tid & 3) * 8;
    *(bf16x8*)&zsm[r * 40 + c8] = *(const bf16x8*)(zin + (size_t)(m0 + r) * 32 + c8);
  }
  __syncthreads();
  rlayer<16,  32, 1, 40, 0,   0, 264, true >(wb + DCMP_W0_OFF, xb0, zsm, nullptr, sA, wv, l15, hi8, rloc); __syncthreads();
  rlayer< 8, 288, 1, 40, 8, 264, 136, true >(wb + DCMP_W1_OFF, xb1, zsm, sA, sB, wv, l15, hi8, rloc); __syncthreads();
  rlayer< 4, 160, 1, 40, 4, 136, 264, true >(wb + DCMP_W2_OFF, xb2, zsm, sB, sA, wv, l15, hi8, rloc); __syncthreads();
  rlayer< 2,  96, 1, 40, 2, 264, 136, true >(wb + DCMP_W3_OFF, xb3, zsm, sA, sB, wv, l15, hi8, rloc); __syncthreads();
  rlayer< 1,  64, 1, 40, 1, 136, 264, true >(wb + DCMP_W4_OFF, xb4, zsm, sB, sA, wv, l15, hi8, rloc);
  for (int i = tid; i < 64 * 16; i += 512) sA[(i >> 4) * 264 + 16 + (i & 15)] = (__bf16)0.0f;
  __syncthreads();
  // final 512-wide layer -> z_stack_hat global (in-place over z_stack)
  rlayer<32,  64, 1, 40, 1, 264, 512, false>(wb + DCMP_W5_OFF, xb5, zsm, sA,
                                             zhout + (size_t)m0 * 512, wv, l15, hi8, rloc);
}

// =============================== decoder (R1 verbatim) =====================
__global__ __launch_bounds__(256, 2)
void dec_kernel(const __bf16* __restrict__ zin, const __bf16* __restrict__ wb,
                const float* __restrict__ b0, const float* __restrict__ b1,
                const float* __restrict__ b2, float* __restrict__ out)
{
  __shared__ __bf16 zs[64][40];
  __shared__ __bf16 h1[64][72];
  __shared__ __bf16 h2[64][136];
  const int e = blockIdx.y;
  const int m0 = blockIdx.x * 64;
  const int tid = threadIdx.x;
  const int lane = tid & 63, wv = tid >> 6;
  const int l15 = lane & 15, hi8 = (lane >> 4) * 8, rloc = (lane >> 4) * 4;

  {
    int r = tid >> 2, c = (tid & 3) * 8;
    *(bf16x8*)&zs[r][c] = *(const bf16x8*)(zin + (size_t)(m0 + r) * 512 + e * 32 + c);
  }
  __syncthreads();

  // L0: N=64, K=32
  {
    const __bf16* W = wb + DEC_W0_OFF + e * 2048;
    f32x4 acc[4];
    float bv = b0[e * 64 + wv * 16 + l15];
    f32x4 bvv = {bv, bv, bv, bv};
    #pragma unroll
    for (int rf = 0; rf < 4; ++rf) acc[rf] = bvv;
    bf16x8 a[4];
    #pragma unroll
    for (int rf = 0; rf < 4; ++rf) a[rf] = *(const bf16x8*)&zs[rf * 16 + l15][hi8];
    bf16x8 bb = *(const bf16x8*)(W + (size_t)(wv * 16 + l15) * 32 + hi8);
    #pragma unroll
    for (int rf = 0; rf < 4; ++rf) acc[rf] = MFMA16(a[rf], bb, acc[rf]);
    #pragma unroll
    for (int rf = 0; rf < 4; ++rf)
      #pragma unroll
      for (int r = 0; r < 4; ++r)
        h1[rf * 16 + rloc + r][wv * 16 + l15] = (__bf16)sigm(acc[rf][r]);
  }
  __syncthreads();

  // L1: N=128, K=64
  {
    const __bf16* W = wb + DEC_W1_OFF + e * 8192;
    f32x4 acc[4][2];
    #pragma unroll
    for (int cf = 0; cf < 2; ++cf) {
      float bv = b1[e * 128 + wv * 32 + cf * 16 + l15];
      f32x4 bvv = {bv, bv, bv, bv};
      #pragma unroll
      for (int rf = 0; rf < 4; ++rf) acc[rf][cf] = bvv;
    }
    #pragma unroll
    for (int ks = 0; ks < 2; ++ks) {
      bf16x8 a[4], bb[2];
      #pragma unroll
      for (int rf = 0; rf < 4; ++rf) a[rf] = *(const bf16x8*)&h1[rf * 16 + l15][ks * 32 + hi8];
      #pragma unroll
      for (int cf = 0; cf < 2; ++cf)
        bb[cf] = *(const bf16x8*)(W + (size_t)(wv * 32 + cf * 16 + l15) * 64 + ks * 32 + hi8);
      #pragma unroll
      for (int rf = 0; rf < 4; ++rf)
        #pragma unroll
        for (int cf = 0; cf < 2; ++cf)
          acc[rf][cf] = MFMA16(a[rf], bb[cf], acc[rf][cf]);
    }
    #pragma unroll
    for (int rf = 0; rf < 4; ++rf)
      #pragma unroll
      for (int cf = 0; cf < 2; ++cf)
        #pragma unroll
        for (int r = 0; r < 4; ++r)
          h2[rf * 16 + rloc + r][wv * 32 + cf * 16 + l15] = (__bf16)sigm(acc[rf][cf][r]);
  }
  __syncthreads();

  // L2: N=256, K=128, no sigmoid, fp32 out
  {
    const __bf16* W = wb + DEC_W2_OFF + e * 32768;
    f32x4 acc[4][4];
    #pragma unroll
    for (int cf = 0; cf < 4; ++cf) {
      float bv = b2[e * 256 + wv * 64 + cf * 16 + l15];
      f32x4 bvv = {bv, bv, bv, bv};
      #pragma unroll
      for (int rf = 0; rf < 4; ++rf) acc[rf][cf] = bvv;
    }
    #pragma unroll
    for (int ks = 0; ks < 4; ++ks) {
      bf16x8 a[4], bb[4];
      #pragma unroll
      for (int rf = 0; rf < 4; ++rf) a[rf] = *(const bf16x8*)&h2[rf * 16 + l15][ks * 32 + hi8];
      #pragma unroll
      for (int cf = 0; cf < 4; ++cf)
        bb[cf] = *(const bf16x8*)(W + (size_t)(wv * 64 + cf * 16 + l15) * 128 + ks * 32 + hi8);
      #pragma unroll
      for (int rf = 0; rf < 4; ++rf)
        #pragma unroll
        for (int cf = 0; cf < 4; ++cf)
          acc[rf][cf] = MFMA16(a[rf], bb[cf], acc[rf][cf]);
    }
    #pragma unroll
    for (int rf = 0; rf < 4; ++rf)
      #pragma unroll
      for (int cf = 0; cf < 4; ++cf)
        #pragma unroll
        for (int r = 0; r < 4; ++r)
          out[(size_t)(m0 + rf * 16 + rloc + r) * 4096 + e * 256 + wv * 64 + cf * 16 + l15] =
              acc[rf][cf][r];
  }
}

// =============================== launcher ==================================
extern "C" void kernel_launch(void* const* d_in, const int* in_sizes, int n_in,
                              void* d_out, int out_size, void* d_ws, size_t ws_size,
                              hipStream_t stream) {
  (void)in_sizes; (void)n_in; (void)out_size; (void)ws_size;
  const float* x   = (const float*)d_in[0];
  const float* ew0 = (const float*)d_in[1];  const float* eb0 = (const float*)d_in[2];
  const float* ew1 = (const float*)d_in[3];  const float* eb1 = (const float*)d_in[4];
  const float* ew2 = (const float*)d_in[5];  const float* eb2 = (const float*)d_in[6];
  const float* dw0 = (const float*)d_in[7];  const float* db0 = (const float*)d_in[8];
  const float* dw1 = (const float*)d_in[9];  const float* db1 = (const float*)d_in[10];
  const float* dw2 = (const float*)d_in[11]; const float* db2 = (const float*)d_in[12];
  const float* cw[6]; const float* cb[6];
  for (int i = 0; i < 6; ++i) { cw[i] = (const float*)d_in[13 + 2 * i]; cb[i] = (const float*)d_in[14 + 2 * i]; }
  const float* xw[6]; const float* xb[6];
  for (int i = 0; i < 6; ++i) { xw[i] = (const float*)d_in[25 + 2 * i]; xb[i] = (const float*)d_in[26 + 2 * i]; }

  __bf16* wbuf   = (__bf16*)d_ws;
  __bf16* zstack = (__bf16*)((char*)d_ws + ZS_BYTES_OFF);  // z_stack, then z_stack_hat in-place
  __bf16* zbuf   = (__bf16*)((char*)d_ws + Z_BYTES_OFF);
  float* out = (float*)d_out;

  prep_kernel<<<1024, 256, 0, stream>>>(ew0, ew1, ew2, dw0, dw1, dw2,
                                        cw[0], cw[1], cw[2], cw[3], cw[4], cw[5],
                                        xw[0], xw[1], xw[2], xw[3], xw[4], xw[5], wbuf);
  enc_kernel<<<dim3(512, 16), 256, 0, stream>>>(x, wbuf, eb0, eb1, eb2, zstack);
  comp_kernel<<<512, 512, 0, stream>>>(zstack, wbuf, cb[0], cb[1], cb[2], cb[3], cb[4], cb[5], zbuf);
  decomp_kernel<<<512, 512, 0, stream>>>(zbuf, wbuf, xb[0], xb[1], xb[2], xb[3], xb[4], xb[5], zstack);
  dec_kernel<<<dim3(512, 16), 256, 0, stream>>>(zstack, wbuf, db0, db1, db2, out);
}

// Round 7
// 469.276 us; speedup vs baseline: 1.3343x; 1.0391x over previous
//
#include <hip/hip_runtime.h>

typedef __bf16 bf16x8 __attribute__((ext_vector_type(8)));
typedef __bf16 bf16x4 __attribute__((ext_vector_type(4)));
typedef float  f32x4  __attribute__((ext_vector_type(4)));

#define MFMA16(a, b, c) __builtin_amdgcn_mfma_f32_16x16x32_bf16((a), (b), (c), 0, 0, 0)

__device__ __forceinline__ float sigm(float x) { return 1.0f / (1.0f + __expf(-x)); }

// ---- packed bf16 weight layout (element offsets inside d_ws) ----
enum : int {
  ENC_W0_OFF  = 0,        // 16 x 128 x 256
  ENC_W1_OFF  = 524288,   // 16 x 64 x 128
  ENC_W2_OFF  = 655360,   // 16 x 32 x 64
  DEC_W0_OFF  = 688128,   // 16 x 64 x 32
  DEC_W1_OFF  = 720896,   // 16 x 128 x 64
  DEC_W2_OFF  = 851968,   // 16 x 256 x 128
  COMP_W0_OFF = 1376256,  // 256 x 512  (folded [z,z])
  COMP_W1_OFF = 1507328,  // 128 x 768
  COMP_W2_OFF = 1605632,  // 64 x 640
  COMP_W3_OFF = 1646592,  // 32 x 576
  COMP_W4_OFF = 1665024,  // 16 x 544
  COMP_W5_OFF = 1673728,  // 32 x 544  (528 padded to 544, pad = 0)
  DCMP_W0_OFF = 1691136,  // 256 x 32  (folded)
  DCMP_W1_OFF = 1699328,  // 128 x 288
  DCMP_W2_OFF = 1736192,  // 64 x 160
  DCMP_W3_OFF = 1746432,  // 32 x 96
  DCMP_W4_OFF = 1749504,  // 16 x 64
  DCMP_W5_OFF = 1750528,  // 512 x 64  (48 padded to 64, pad = 0)
  W_TOTAL     = 1783296,
};

#define ZS_BYTES_OFF (4u * 1024u * 1024u)            // z_stack / z_stack_hat: 32 MB
#define Z_BYTES_OFF  (ZS_BYTES_OFF + 33554432u)      // z: 2 MB

// =============================== weight prep ===============================
__global__ void prep_kernel(
    const float* __restrict__ ew0, const float* __restrict__ ew1, const float* __restrict__ ew2,
    const float* __restrict__ dw0, const float* __restrict__ dw1, const float* __restrict__ dw2,
    const float* __restrict__ cw0, const float* __restrict__ cw1, const float* __restrict__ cw2,
    const float* __restrict__ cw3, const float* __restrict__ cw4, const float* __restrict__ cw5,
    const float* __restrict__ xw0, const float* __restrict__ xw1, const float* __restrict__ xw2,
    const float* __restrict__ xw3, const float* __restrict__ xw4, const float* __restrict__ xw5,
    __bf16* __restrict__ wb)
{
  for (int i = blockIdx.x * blockDim.x + threadIdx.x; i < W_TOTAL; i += gridDim.x * blockDim.x) {
    float v;
    if      (i < ENC_W1_OFF)  v = ew0[i - ENC_W0_OFF];
    else if (i < ENC_W2_OFF)  v = ew1[i - ENC_W1_OFF];
    else if (i < DEC_W0_OFF)  v = ew2[i - ENC_W2_OFF];
    else if (i < DEC_W1_OFF)  v = dw0[i - DEC_W0_OFF];
    else if (i < DEC_W2_OFF)  v = dw1[i - DEC_W1_OFF];
    else if (i < COMP_W0_OFF) v = dw2[i - DEC_W2_OFF];
    else if (i < COMP_W1_OFF) { int t = i - COMP_W0_OFF; int o = t >> 9, c = t & 511;
                                v = cw0[o * 1024 + c] + cw0[o * 1024 + 512 + c]; }
    else if (i < COMP_W2_OFF) v = cw1[i - COMP_W1_OFF];
    else if (i < COMP_W3_OFF) v = cw2[i - COMP_W2_OFF];
    else if (i < COMP_W4_OFF) v = cw3[i - COMP_W3_OFF];
    else if (i < COMP_W5_OFF) v = cw4[i - COMP_W4_OFF];
    else if (i < DCMP_W0_OFF) { int t = i - COMP_W5_OFF; int o = t / 544, c = t % 544;
                                v = (c < 528) ? cw5[o * 528 + c] : 0.0f; }
    else if (i < DCMP_W1_OFF) { int t = i - DCMP_W0_OFF; int o = t >> 5, c = t & 31;
                                v = xw0[o * 64 + c] + xw0[o * 64 + 32 + c]; }
    else if (i < DCMP_W2_OFF) v = xw1[i - DCMP_W1_OFF];
    else if (i < DCMP_W3_OFF) v = xw2[i - DCMP_W2_OFF];
    else if (i < DCMP_W4_OFF) v = xw3[i - DCMP_W3_OFF];
    else if (i < DCMP_W5_OFF) v = xw4[i - DCMP_W4_OFF];
    else                      { int t = i - DCMP_W5_OFF; int o = t >> 6, c = t & 63;
                                v = (c < 48) ? xw5[o * 48 + c] : 0.0f; }
    wb[i] = (__bf16)v;
  }
}

// =============================== encoder ===================================
// R1 structure; single change: h2 aliases the dead xs region -> 50.6 KB LDS
// -> 3 blocks/CU (was 2). xs last read in L0, barrier, then h2 written.
__global__ __launch_bounds__(256, 3)
void enc_kernel(const float* __restrict__ x, const __bf16* __restrict__ wb,
                const float* __restrict__ b0, const float* __restrict__ b1,
                const float* __restrict__ b2, __bf16* __restrict__ zout)
{
  __shared__ __align__(16) char smem[51200];
  __bf16* xs = (__bf16*)smem;            // [64][264], dead after L0
  __bf16* h1 = (__bf16*)(smem + 33792);  // [64][136]
  __bf16* h2 = (__bf16*)smem;            // [64][72], aliases xs
  const int e = blockIdx.y;
  const int m0 = blockIdx.x * 64;
  const int tid = threadIdx.x;
  const int lane = tid & 63, wv = tid >> 6;
  const int l15 = lane & 15, hi8 = (lane >> 4) * 8, rloc = (lane >> 4) * 4;

  const float* xblk = x + (size_t)m0 * 4096 + e * 256;
  #pragma unroll
  for (int i = 0; i < 16; ++i) {
    int idx = tid + i * 256;
    int r = idx >> 6, c4 = (idx & 63) * 4;
    float4 v = *(const float4*)(xblk + (size_t)r * 4096 + c4);
    bf16x4 o = { (__bf16)v.x, (__bf16)v.y, (__bf16)v.z, (__bf16)v.w };
    *(bf16x4*)&xs[r * 264 + c4] = o;
  }
  __syncthreads();

  // L0: N=128, K=256. wave covers cols [wv*32, wv*32+32)
  {
    const __bf16* W = wb + ENC_W0_OFF + e * 32768;
    f32x4 acc[4][2];
    #pragma unroll
    for (int cf = 0; cf < 2; ++cf) {
      float bv = b0[e * 128 + wv * 32 + cf * 16 + l15];
      f32x4 bvv = {bv, bv, bv, bv};
      #pragma unroll
      for (int rf = 0; rf < 4; ++rf) acc[rf][cf] = bvv;
    }
    #pragma unroll
    for (int ks = 0; ks < 8; ++ks) {
      bf16x8 a[4], bb[2];
      #pragma unroll
      for (int rf = 0; rf < 4; ++rf) a[rf] = *(const bf16x8*)&xs[(rf * 16 + l15) * 264 + ks * 32 + hi8];
      #pragma unroll
      for (int cf = 0; cf < 2; ++cf)
        bb[cf] = *(const bf16x8*)(W + (size_t)(wv * 32 + cf * 16 + l15) * 256 + ks * 32 + hi8);
      #pragma unroll
      for (int rf = 0; rf < 4; ++rf)
        #pragma unroll
        for (int cf = 0; cf < 2; ++cf)
          acc[rf][cf] = MFMA16(a[rf], bb[cf], acc[rf][cf]);
    }
    #pragma unroll
    for (int rf = 0; rf < 4; ++rf)
      #pragma unroll
      for (int cf = 0; cf < 2; ++cf)
        #pragma unroll
        for (int r = 0; r < 4; ++r)
          h1[(rf * 16 + rloc + r) * 136 + wv * 32 + cf * 16 + l15] = (__bf16)sigm(acc[rf][cf][r]);
  }
  __syncthreads();

  // L1: N=64, K=128. h2 overwrites the xs alias region (xs fully dead).
  {
    const __bf16* W = wb + ENC_W1_OFF + e * 8192;
    f32x4 acc[4];
    float bv = b1[e * 64 + wv * 16 + l15];
    f32x4 bvv = {bv, bv, bv, bv};
    #pragma unroll
    for (int rf = 0; rf < 4; ++rf) acc[rf] = bvv;
    #pragma unroll
    for (int ks = 0; ks < 4; ++ks) {
      bf16x8 a[4];
      #pragma unroll
      for (int rf = 0; rf < 4; ++rf) a[rf] = *(const bf16x8*)&h1[(rf * 16 + l15) * 136 + ks * 32 + hi8];
      bf16x8 bb = *(const bf16x8*)(W + (size_t)(wv * 16 + l15) * 128 + ks * 32 + hi8);
      #pragma unroll
      for (int rf = 0; rf < 4; ++rf) acc[rf] = MFMA16(a[rf], bb, acc[rf]);
    }
    #pragma unroll
    for (int rf = 0; rf < 4; ++rf)
      #pragma unroll
      for (int r = 0; r < 4; ++r)
        h2[(rf * 16 + rloc + r) * 72 + wv * 16 + l15] = (__bf16)sigm(acc[rf][r]);
  }
  __syncthreads();

  // L2: N=32, K=64, no sigmoid. waves 0,1 only.
  if (wv < 2) {
    const __bf16* W = wb + ENC_W2_OFF + e * 2048;
    f32x4 acc[4];
    float bv = b2[e * 32 + wv * 16 + l15];
    f32x4 bvv = {bv, bv, bv, bv};
    #pragma unroll
    for (int rf = 0; rf < 4; ++rf) acc[rf] = bvv;
    #pragma unroll
    for (int ks = 0; ks < 2; ++ks) {
      bf16x8 a[4];
      #pragma unroll
      for (int rf = 0; rf < 4; ++rf) a[rf] = *(const bf16x8*)&h2[(rf * 16 + l15) * 72 + ks * 32 + hi8];
      bf16x8 bb = *(const bf16x8*)(W + (size_t)(wv * 16 + l15) * 64 + ks * 32 + hi8);
      #pragma unroll
      for (int rf = 0; rf < 4; ++rf) acc[rf] = MFMA16(a[rf], bb, acc[rf]);
    }
    #pragma unroll
    for (int rf = 0; rf < 4; ++rf)
      #pragma unroll
      for (int r = 0; r < 4; ++r)
        zout[(size_t)(m0 + rf * 16 + rloc + r) * 512 + e * 32 + wv * 16 + l15] = (__bf16)acc[rf][r];
  }
}

// ==================== 8-wave residual layer (R4-verified) ==================
template<int NF, int KT, int ZKS, int ZLD, int SKS, int SLD, int DLD, bool SIG>
__device__ __forceinline__ void rlayer(const __bf16* __restrict__ W, const float* __restrict__ bias,
                                       const __bf16* __restrict__ zp, const __bf16* __restrict__ sp,
                                       __bf16* __restrict__ dst,
                                       int wv, int l15, int hi8, int rloc)
{
  constexpr int NJ = (NF >= 32) ? 4 : ((NF >= 16) ? 2 : 1);
  constexpr int NR = (NF >= 8) ? 4 : ((NF == 4) ? 2 : 1);
  int c0, row0;
  if constexpr (NF >= 8)       { c0 = wv;      row0 = 0; }
  else if constexpr (NF == 4)  { c0 = wv & 3;  row0 = (wv >> 2) * 32; }
  else if constexpr (NF == 2)  { c0 = wv & 1;  row0 = (wv >> 1) * 16; }
  else                         { if (wv >= 4) return; c0 = 0; row0 = wv * 16; }
  f32x4 acc[NR][NJ];
  #pragma unroll
  for (int j = 0; j < NJ; ++j) {
    float bv = bias[(c0 + 8 * j) * 16 + l15];
    f32x4 b4 = {bv, bv, bv, bv};
    #pragma unroll
    for (int rf = 0; rf < NR; ++rf) acc[rf][j] = b4;
  }
  #pragma unroll
  for (int ks = 0; ks < ZKS; ++ks) {
    bf16x8 a[NR];
    #pragma unroll
    for (int rf = 0; rf < NR; ++rf)
      a[rf] = *(const bf16x8*)&zp[(size_t)(row0 + rf * 16 + l15) * ZLD + ks * 32 + hi8];
    #pragma unroll
    for (int j = 0; j < NJ; ++j) {
      bf16x8 b = *(const bf16x8*)&W[(size_t)((c0 + 8 * j) * 16 + l15) * KT + ks * 32 + hi8];
      #pragma unroll
      for (int rf = 0; rf < NR; ++rf) acc[rf][j] = MFMA16(a[rf], b, acc[rf][j]);
    }
  }
  if constexpr (SKS > 0) {
    #pragma unroll
    for (int ks = 0; ks < SKS; ++ks) {
      bf16x8 a[NR];
      #pragma unroll
      for (int rf = 0; rf < NR; ++rf)
        a[rf] = *(const bf16x8*)&sp[(size_t)(row0 + rf * 16 + l15) * SLD + ks * 32 + hi8];
      #pragma unroll
      for (int j = 0; j < NJ; ++j) {
        bf16x8 b = *(const bf16x8*)&W[(size_t)((c0 + 8 * j) * 16 + l15) * KT + ZKS * 32 + ks * 32 + hi8];
        #pragma unroll
        for (int rf = 0; rf < NR; ++rf) acc[rf][j] = MFMA16(a[rf], b, acc[rf][j]);
      }
    }
  }
  #pragma unroll
  for (int j = 0; j < NJ; ++j)
    #pragma unroll
    for (int rf = 0; rf < NR; ++rf)
      #pragma unroll
      for (int r = 0; r < 4; ++r) {
        float v = acc[rf][j][r];
        dst[(size_t)(row0 + rf * 16 + rloc + r) * DLD + (c0 + 8 * j) * 16 + l15] =
            (__bf16)(SIG ? sigm(v) : v);
      }
}

// =============================== compressor ================================
__global__ __launch_bounds__(512, 2)
void comp_kernel(const __bf16* __restrict__ zin, const __bf16* __restrict__ wb,
                 const float* __restrict__ cb0, const float* __restrict__ cb1,
                 const float* __restrict__ cb2, const float* __restrict__ cb3,
                 const float* __restrict__ cb4, const float* __restrict__ cb5,
                 __bf16* __restrict__ zout)
{
  __shared__ __bf16 zs[64 * 520];
  __shared__ __bf16 sA[64 * 264];
  __shared__ __bf16 sB[64 * 136];
  const int tid = threadIdx.x;
  const int wv = tid >> 6, lane = tid & 63;
  const int l15 = lane & 15, hi8 = (lane >> 4) * 8, rloc = (lane >> 4) * 4;
  const int m0 = blockIdx.x * 64;

  #pragma unroll
  for (int i = 0; i < 8; ++i) {
    int idx = tid + i * 512;
    int r = idx >> 6, c8 = (idx & 63) * 8;
    *(bf16x8*)&zs[r * 520 + c8] = *(const bf16x8*)(zin + (size_t)(m0 + r) * 512 + c8);
  }
  __syncthreads();
  rlayer<16, 512, 16, 520, 0,   0, 264, true >(wb + COMP_W0_OFF, cb0, zs, nullptr, sA, wv, l15, hi8, rloc); __syncthreads();
  rlayer< 8, 768, 16, 520, 8, 264, 136, true >(wb + COMP_W1_OFF, cb1, zs, sA, sB, wv, l15, hi8, rloc); __syncthreads();
  rlayer< 4, 640, 16, 520, 4, 136, 264, true >(wb + COMP_W2_OFF, cb2, zs, sB, sA, wv, l15, hi8, rloc); __syncthreads();
  rlayer< 2, 576, 16, 520, 2, 264, 136, true >(wb + COMP_W3_OFF, cb3, zs, sA, sB, wv, l15, hi8, rloc); __syncthreads();
  rlayer< 1, 544, 16, 520, 1, 136, 264, true >(wb + COMP_W4_OFF, cb4, zs, sB, sA, wv, l15, hi8, rloc);
  for (int i = tid; i < 64 * 16; i += 512) sA[(i >> 4) * 264 + 16 + (i & 15)] = (__bf16)0.0f;
  __syncthreads();
  rlayer< 2, 544, 16, 520, 1, 264, 32, false>(wb + COMP_W5_OFF, cb5, zs, sA,
                                              zout + (size_t)m0 * 32, wv, l15, hi8, rloc);
}

// =============================== decompressor ==============================
__global__ __launch_bounds__(512, 4)
void decomp_kernel(const __bf16* __restrict__ zin, const __bf16* __restrict__ wb,
                   const float* __restrict__ xb0, const float* __restrict__ xb1,
                   const float* __restrict__ xb2, const float* __restrict__ xb3,
                   const float* __restrict__ xb4, const float* __restrict__ xb5,
                   __bf16* __restrict__ zhout)
{
  __shared__ __bf16 zsm[64 * 40];
  __shared__ __bf16 sA[64 * 264];
  __shared__ __bf16 sB[64 * 136];
  const int tid = threadIdx.x;
  const int wv = tid >> 6, lane = tid & 63;
  const int l15 = lane & 15, hi8 = (lane >> 4) * 8, rloc = (lane >> 4) * 4;
  const int m0 = blockIdx.x * 64;

  if (tid < 256) {
    int r = tid >> 2, c8 = (tid & 3) * 8;
    *(bf16x8*)&zsm[r * 40 + c8] = *(const bf16x8*)(zin + (size_t)(m0 + r) * 32 + c8);
  }
  __syncthreads();
  rlayer<16,  32, 1, 40, 0,   0, 264, true >(wb + DCMP_W0_OFF, xb0, zsm, nullptr, sA, wv, l15, hi8, rloc); __syncthreads();
  rlayer< 8, 288, 1, 40, 8, 264, 136, true >(wb + DCMP_W1_OFF, xb1, zsm, sA, sB, wv, l15, hi8, rloc); __syncthreads();
  rlayer< 4, 160, 1, 40, 4, 136, 264, true >(wb + DCMP_W2_OFF, xb2, zsm, sB, sA, wv, l15, hi8, rloc); __syncthreads();
  rlayer< 2,  96, 1, 40, 2, 264, 136, true >(wb + DCMP_W3_OFF, xb3, zsm, sA, sB, wv, l15, hi8, rloc); __syncthreads();
  rlayer< 1,  64, 1, 40, 1, 136, 264, true >(wb + DCMP_W4_OFF, xb4, zsm, sB, sA, wv, l15, hi8, rloc);
  for (int i = tid; i < 64 * 16; i += 512) sA[(i >> 4) * 264 + 16 + (i & 15)] = (__bf16)0.0f;
  __syncthreads();
  rlayer<32,  64, 1, 40, 1, 264, 512, false>(wb + DCMP_W5_OFF, xb5, zsm, sA,
                                             zhout + (size_t)m0 * 512, wv, l15, hi8, rloc);
}

// =============================== decoder ===================================
// R1 structure; single change: __launch_bounds__(256,4) caps VGPR at 128 so
// 4 blocks/CU become resident (LDS 31.7 KB allows it; bound=2 let VGPR >128).
__global__ __launch_bounds__(256, 4)
void dec_kernel(const __bf16* __restrict__ zin, const __bf16* __restrict__ wb,
                const float* __restrict__ b0, const float* __restrict__ b1,
                const float* __restrict__ b2, float* __restrict__ out)
{
  __shared__ __bf16 zs[64][40];
  __shared__ __bf16 h1[64][72];
  __shared__ __bf16 h2[64][136];
  const int e = blockIdx.y;
  const int m0 = blockIdx.x * 64;
  const int tid = threadIdx.x;
  const int lane = tid & 63, wv = tid >> 6;
  const int l15 = lane & 15, hi8 = (lane >> 4) * 8, rloc = (lane >> 4) * 4;

  {
    int r = tid >> 2, c = (tid & 3) * 8;
    *(bf16x8*)&zs[r][c] = *(const bf16x8*)(zin + (size_t)(m0 + r) * 512 + e * 32 + c);
  }
  __syncthreads();

  // L0: N=64, K=32
  {
    const __bf16* W = wb + DEC_W0_OFF + e * 2048;
    f32x4 acc[4];
    float bv = b0[e * 64 + wv * 16 + l15];
    f32x4 bvv = {bv, bv, bv, bv};
    #pragma unroll
    for (int rf = 0; rf < 4; ++rf) acc[rf] = bvv;
    bf16x8 a[4];
    #pragma unroll
    for (int rf = 0; rf < 4; ++rf) a[rf] = *(const bf16x8*)&zs[rf * 16 + l15][hi8];
    bf16x8 bb = *(const bf16x8*)(W + (size_t)(wv * 16 + l15) * 32 + hi8);
    #pragma unroll
    for (int rf = 0; rf < 4; ++rf) acc[rf] = MFMA16(a[rf], bb, acc[rf]);
    #pragma unroll
    for (int rf = 0; rf < 4; ++rf)
      #pragma unroll
      for (int r = 0; r < 4; ++r)
        h1[rf * 16 + rloc + r][wv * 16 + l15] = (__bf16)sigm(acc[rf][r]);
  }
  __syncthreads();

  // L1: N=128, K=64
  {
    const __bf16* W = wb + DEC_W1_OFF + e * 8192;
    f32x4 acc[4][2];
    #pragma unroll
    for (int cf = 0; cf < 2; ++cf) {
      float bv = b1[e * 128 + wv * 32 + cf * 16 + l15];
      f32x4 bvv = {bv, bv, bv, bv};
      #pragma unroll
      for (int rf = 0; rf < 4; ++rf) acc[rf][cf] = bvv;
    }
    #pragma unroll
    for (int ks = 0; ks < 2; ++ks) {
      bf16x8 a[4], bb[2];
      #pragma unroll
      for (int rf = 0; rf < 4; ++rf) a[rf] = *(const bf16x8*)&h1[rf * 16 + l15][ks * 32 + hi8];
      #pragma unroll
      for (int cf = 0; cf < 2; ++cf)
        bb[cf] = *(const bf16x8*)(W + (size_t)(wv * 32 + cf * 16 + l15) * 64 + ks * 32 + hi8);
      #pragma unroll
      for (int rf = 0; rf < 4; ++rf)
        #pragma unroll
        for (int cf = 0; cf < 2; ++cf)
          acc[rf][cf] = MFMA16(a[rf], bb[cf], acc[rf][cf]);
    }
    #pragma unroll
    for (int rf = 0; rf < 4; ++rf)
      #pragma unroll
      for (int cf = 0; cf < 2; ++cf)
        #pragma unroll
        for (int r = 0; r < 4; ++r)
          h2[rf * 16 + rloc + r][wv * 32 + cf * 16 + l15] = (__bf16)sigm(acc[rf][cf][r]);
  }
  __syncthreads();

  // L2: N=256, K=128, no sigmoid, fp32 out
  {
    const __bf16* W = wb + DEC_W2_OFF + e * 32768;
    f32x4 acc[4][4];
    #pragma unroll
    for (int cf = 0; cf < 4; ++cf) {
      float bv = b2[e * 256 + wv * 64 + cf * 16 + l15];
      f32x4 bvv = {bv, bv, bv, bv};
      #pragma unroll
      for (int rf = 0; rf < 4; ++rf) acc[rf][cf] = bvv;
    }
    #pragma unroll
    for (int ks = 0; ks < 4; ++ks) {
      bf16x8 a[4], bb[4];
      #pragma unroll
      for (int rf = 0; rf < 4; ++rf) a[rf] = *(const bf16x8*)&h2[rf * 16 + l15][ks * 32 + hi8];
      #pragma unroll
      for (int cf = 0; cf < 4; ++cf)
        bb[cf] = *(const bf16x8*)(W + (size_t)(wv * 64 + cf * 16 + l15) * 128 + ks * 32 + hi8);
      #pragma unroll
      for (int rf = 0; rf < 4; ++rf)
        #pragma unroll
        for (int cf = 0; cf < 4; ++cf)
          acc[rf][cf] = MFMA16(a[rf], bb[cf], acc[rf][cf]);
    }
    #pragma unroll
    for (int rf = 0; rf < 4; ++rf)
      #pragma unroll
      for (int cf = 0; cf < 4; ++cf)
        #pragma unroll
        for (int r = 0; r < 4; ++r)
          out[(size_t)(m0 + rf * 16 + rloc + r) * 4096 + e * 256 + wv * 64 + cf * 16 + l15] =
              acc[rf][cf][r];
  }
}

// =============================== launcher ==================================
extern "C" void kernel_launch(void* const* d_in, const int* in_sizes, int n_in,
                              void* d_out, int out_size, void* d_ws, size_t ws_size,
                              hipStream_t stream) {
  (void)in_sizes; (void)n_in; (void)out_size; (void)ws_size;
  const float* x   = (const float*)d_in[0];
  const float* ew0 = (const float*)d_in[1];  const float* eb0 = (const float*)d_in[2];
  const float* ew1 = (const float*)d_in[3];  const float* eb1 = (const float*)d_in[4];
  const float* ew2 = (const float*)d_in[5];  const float* eb2 = (const float*)d_in[6];
  const float* dw0 = (const float*)d_in[7];  const float* db0 = (const float*)d_in[8];
  const float* dw1 = (const float*)d_in[9];  const float* db1 = (const float*)d_in[10];
  const float* dw2 = (const float*)d_in[11]; const float* db2 = (const float*)d_in[12];
  const float* cw[6]; const float* cb[6];
  for (int i = 0; i < 6; ++i) { cw[i] = (const float*)d_in[13 + 2 * i]; cb[i] = (const float*)d_in[14 + 2 * i]; }
  const float* xw[6]; const float* xb[6];
  for (int i = 0; i < 6; ++i) { xw[i] = (const float*)d_in[25 + 2 * i]; xb[i] = (const float*)d_in[26 + 2 * i]; }

  __bf16* wbuf   = (__bf16*)d_ws;
  __bf16* zstack = (__bf16*)((char*)d_ws + ZS_BYTES_OFF);  // z_stack, then z_stack_hat in-place
  __bf16* zbuf   = (__bf16*)((char*)d_ws + Z_BYTES_OFF);
  float* out = (float*)d_out;

  prep_kernel<<<1024, 256, 0, stream>>>(ew0, ew1, ew2, dw0, dw1, dw2,
                                        cw[0], cw[1], cw[2], cw[3], cw[4], cw[5],
                                        xw[0], xw[1], xw[2], xw[3], xw[4], xw[5], wbuf);
  enc_kernel<<<dim3(512, 16), 256, 0, stream>>>(x, wbuf, eb0, eb1, eb2, zstack);
  comp_kernel<<<512, 512, 0, stream>>>(zstack, wbuf, cb[0], cb[1], cb[2], cb[3], cb[4], cb[5], zbuf);
  decomp_kernel<<<512, 512, 0, stream>>>(zbuf, wbuf, xb[0], xb[1], xb[2], xb[3], xb[4], xb[5], zstack);
  dec_kernel<<<dim3(512, 16), 256, 0, stream>>>(zstack, wbuf, db0, db1, db2, out);
}